// Round 8
// baseline (27.944 us; speedup 1.0000x reference)
//
#include <hip/hip_runtime.h>

#define NBOX 8192
#define MAXDET 100
#define SCORE_T 0.05f
#define NMS_T 0.5f
#define CAP 1024
#define KTGT 128
#define TOPBIN_T 0.99609375f   // 255/256 — exact: s>=T  <=>  (int)(s*256.f)==255 for s<1
#define BT2 256

typedef unsigned long long u64;

// ws layout (bytes)
#define WS_KEYS 0u         // u32[8192]   32KB
#define WS_CNTS 32768u     // u32[64]
#define WS_KIDX 36864u     // u64[8192]   64KB
#define WS_B0   102400u    // float4[8192] 128KB
#define WS_KP0  233472u    // float4[8192] 128KB
#define WS_KP1  364544u    // float4[8192] 128KB
#define WS_DD   495616u    // float4[8192] 128KB

__device__ __forceinline__ float rl_f(float v, int j) {
    return __int_as_float(__builtin_amdgcn_readlane(__float_as_int(v), j));
}

__device__ __forceinline__ float iou_fn(float x1, float y1, float x2, float y2, float area,
                                        float bx1, float by1, float bx2, float by2, float barea) {
    float iw = fminf(x2, bx2) - fmaxf(x1, bx1);
    float ih = fminf(y2, by2) - fmaxf(y1, by1);
    iw = fmaxf(iw, 0.0f);
    ih = fmaxf(ih, 0.0f);
    float inter = iw * ih;
    return inter / fmaxf(area + barea - inter, 1e-8f);
}

__device__ __forceinline__ void bins_of(unsigned k, int& b1, int& b2) {
    float s = __uint_as_float(k & 0x7FFFFFFFu);
    b1 = (int)(s * 256.0f); if (b1 > 255) b1 = 255;
    b2 = (int)(s * 65536.0f) & 255;
}

// ---- K1: chip-parallel score + full-payload push of top-bin candidates ----
__global__ __launch_bounds__(128) void score_push_kernel(
    const float* __restrict__ boxes, const float* __restrict__ dims,
    const float* __restrict__ cls, unsigned* __restrict__ keys,
    unsigned* __restrict__ cnts, u64* __restrict__ kidx,
    float4* __restrict__ b0a, float4* __restrict__ kp0a,
    float4* __restrict__ kp1a, float4* __restrict__ dda) {
    __shared__ int s_lcnt;
    const int t = threadIdx.x, blk = blockIdx.x;
    const int i = blk * 128 + t;
    if (t == 0) s_lcnt = 0;
    __syncthreads();
    const float4 c0 = *reinterpret_cast<const float4*>(cls + i * 8);
    const float4 c1 = *reinterpret_cast<const float4*>(cls + i * 8 + 4);
    float m0 = fmaxf(c0.x, c1.x), m1 = fmaxf(c0.y, c1.y);
    float m2 = fmaxf(c0.z, c1.z), m3 = fmaxf(c0.w, c1.w);
    float s = fmaxf(fmaxf(m0, m1), fmaxf(m2, m3));
    unsigned u = __float_as_uint(s);
    unsigned key = (u >> 31) ? ~u : (u | 0x80000000u);
    key = (s > SCORE_T) ? key : 0u;
    keys[i] = key;
    if (key && s >= TOPBIN_T) {
        int o = 0; float best = m0;
        if (m1 > best) { best = m1; o = 1; }
        if (m2 > best) { best = m2; o = 2; }
        if (m3 > best) { best = m3; o = 3; }
        int pos = atomicAdd(&s_lcnt, 1);
        int slot = blk * 128 + pos;
        kidx[slot] = (((u64)key) << 27) | (((u64)(NBOX - 1 - i)) << 14) | (unsigned)slot;
        const float4* br = reinterpret_cast<const float4*>(boxes + i * 12);
        b0a[slot] = br[0];
        kp0a[slot] = br[1];
        kp1a[slot] = br[2];
        dda[slot] = make_float4(dims[i * 3], dims[i * 3 + 1], dims[i * 3 + 2], (float)o);
    }
    __syncthreads();
    if (t == 0) cnts[blk] = (unsigned)s_lcnt;
}

// ---- K2: gather + rank-sort + exact greedy NMS + output ----
__global__ __launch_bounds__(BT2) void nms_out_kernel(
    const float* __restrict__ boxes, const float* __restrict__ dims,
    const float* __restrict__ cls, const unsigned* __restrict__ keysG,
    const unsigned* __restrict__ cnts, const u64* __restrict__ kidxG,
    const float4* __restrict__ b0a, const float4* __restrict__ kp0a,
    const float4* __restrict__ kp1a, const float4* __restrict__ dda,
    float* __restrict__ out) {
    __shared__ unsigned s_key[NBOX];           // 32KB (fallback only)
    __shared__ unsigned s_hist[256];
    __shared__ unsigned s_off[65];
    __shared__ u64 s_sel[CAP];                 // 8KB
    __shared__ u64 s_srt[CAP];                 // 8KB
    __shared__ unsigned short s_srtpos[CAP];   // 2KB
    __shared__ float4 s_cb[CAP];               // 16KB
    __shared__ float4 s_bb[128];
    __shared__ float s_bar[128];
    __shared__ float4 s_kb[MAXDET];
    __shared__ float s_karea[MAXDET];
    __shared__ u64 s_kv[MAXDET];
    __shared__ int s_kc, s_cnt, s_B1, s_B2, s_state, s_refKrem;
    __shared__ u64 s_alive0;

    const int tid = threadIdx.x;
    const int lane = tid & 63;
    const int wid = tid >> 6;

    auto rank_scatter = [&](int sc, bool loadBox) {
        for (int t = tid; t < sc; t += BT2) {
            u64 mine = s_sel[t];
            float4 pb = make_float4(0.f, 0.f, 0.f, 0.f);
            if (loadBox) {
                int bidx = NBOX - 1 - (int)((mine >> 14) & 8191ull);
                pb = *reinterpret_cast<const float4*>(boxes + bidx * 12);
            }
            int rank = 0;
            int j = 0;
            for (; j + 8 <= sc; j += 8) {
                u64 a0 = s_sel[j + 0], a1 = s_sel[j + 1], a2 = s_sel[j + 2], a3 = s_sel[j + 3];
                u64 a4 = s_sel[j + 4], a5 = s_sel[j + 5], a6 = s_sel[j + 6], a7 = s_sel[j + 7];
                rank += (int)(a0 > mine) + (int)(a1 > mine) + (int)(a2 > mine) + (int)(a3 > mine)
                      + (int)(a4 > mine) + (int)(a5 > mine) + (int)(a6 > mine) + (int)(a7 > mine);
            }
            for (; j < sc; ++j) rank += (s_sel[j] > mine) ? 1 : 0;
            s_srt[rank] = mine;
            s_srtpos[rank] = (unsigned short)t;
            if (loadBox) s_cb[t] = pb;
        }
    };

    auto nms_groups = [&](int scN) {
        for (int base = 0; base < scN && s_kc < MAXDET; base += 128) {
            const int kc0 = s_kc;
            float x1 = 0.f, y1 = 0.f, x2 = 0.f, y2 = 0.f, area = 0.f;
            u64 v = 0ull; bool have = false;
            if (wid < 2) {
                int p = base + wid * 64 + lane;
                have = p < scN;
                v = have ? s_srt[p] : 0ull;
                int cp = have ? (int)s_srtpos[p] : 0;
                float4 b = s_cb[cp];
                if (have) { x1 = b.x; y1 = b.y; x2 = b.z; y2 = b.w; area = (x2 - x1) * (y2 - y1); }
                int sl = wid * 64 + lane;
                s_bb[sl] = make_float4(x1, y1, x2, y2); s_bar[sl] = area;
            }
            __syncthreads();
            if (wid == 0) {
                bool cand = have;
                for (int k = 0; k < kc0; ++k) {
                    float4 kb = s_kb[k];
                    float iou = iou_fn(x1, y1, x2, y2, area, kb.x, kb.y, kb.z, kb.w, s_karea[k]);
                    cand = cand && !(iou > NMS_T);
                }
                u64 m = 0ull;
#pragma unroll 8
                for (int j = 0; j < 64; ++j) {
                    float iou = iou_fn(x1, y1, x2, y2, area,
                                       rl_f(x1, j), rl_f(y1, j), rl_f(x2, j), rl_f(y2, j), rl_f(area, j));
                    if ((iou > NMS_T) && (j < lane)) m |= (1ull << j);
                }
                u64 alive = __ballot(cand);
                u64 conf = __ballot((m & alive) != 0ull) & alive;
                while (conf) {
                    int i = (int)__builtin_ctzll(conf);
                    bool deadI = (lane == i) && ((m & alive) != 0ull);
                    u64 d = __ballot(deadI);
                    alive &= ~d; conf &= ~(d | (1ull << i));
                }
                int rank = (int)__popcll(alive & ((1ull << lane) - 1ull));
                int slot = kc0 + rank;
                if (((alive >> lane) & 1ull) && slot < MAXDET) {
                    s_kb[slot] = make_float4(x1, y1, x2, y2);
                    s_karea[slot] = area; s_kv[slot] = v;
                }
                if (lane == 0) s_alive0 = alive;
            }
            u64 m_low = 0ull, m_high = 0ull;
            bool cand1 = have;
            if (wid == 1) {
                for (int k = 0; k < kc0; ++k) {
                    float4 kb = s_kb[k];
                    float iou = iou_fn(x1, y1, x2, y2, area, kb.x, kb.y, kb.z, kb.w, s_karea[k]);
                    cand1 = cand1 && !(iou > NMS_T);
                }
#pragma unroll 8
                for (int j = 0; j < 64; ++j) {
                    float4 bb = s_bb[j];
                    float iou = iou_fn(x1, y1, x2, y2, area, bb.x, bb.y, bb.z, bb.w, s_bar[j]);
                    if (iou > NMS_T) m_low |= (1ull << j);
                }
#pragma unroll 8
                for (int j = 0; j < 64; ++j) {
                    float iou = iou_fn(x1, y1, x2, y2, area,
                                       rl_f(x1, j), rl_f(y1, j), rl_f(x2, j), rl_f(y2, j), rl_f(area, j));
                    if ((iou > NMS_T) && (j < lane)) m_high |= (1ull << j);
                }
            }
            __syncthreads();
            if (wid == 1) {
                u64 alive0 = s_alive0;
                int popc0 = (int)__popcll(alive0);
                bool cand = cand1 && ((m_low & alive0) == 0ull);
                u64 alive = __ballot(cand);
                u64 conf = __ballot((m_high & alive) != 0ull) & alive;
                while (conf) {
                    int i = (int)__builtin_ctzll(conf);
                    bool deadI = (lane == i) && ((m_high & alive) != 0ull);
                    u64 d = __ballot(deadI);
                    alive &= ~d; conf &= ~(d | (1ull << i));
                }
                int rank = (int)__popcll(alive & ((1ull << lane) - 1ull));
                int slot = kc0 + popc0 + rank;
                if (((alive >> lane) & 1ull) && slot < MAXDET) {
                    s_kb[slot] = make_float4(x1, y1, x2, y2);
                    s_karea[slot] = area; s_kv[slot] = v;
                }
                if (lane == 0) {
                    int nk = kc0 + popc0 + (int)__popcll(alive);
                    s_kc = nk > MAXDET ? MAXDET : nk;
                }
            }
            __syncthreads();
        }
    };

    // ---- prefix over per-block counts (wave 0) ----
    if (tid == 0) { s_kc = 0; s_cnt = 0; }
    if (wid == 0) {
        unsigned acc = cnts[lane];
#pragma unroll
        for (int d = 1; d < 64; d <<= 1) {
            unsigned o = __shfl_up(acc, d);
            if (lane >= d) acc += o;
        }
        s_off[lane + 1] = acc;
        if (lane == 0) s_off[0] = 0u;
    }
    __syncthreads();
    const int sc = (int)s_off[64];
    const bool fast = (sc > 0 && sc <= CAP);

    // ---- FAST PATH: gather pushed candidates, sort, NMS ----
    if (fast) {
        const int r = tid >> 2;
        const unsigned o_r = s_off[r];
        const int c_r = (int)(s_off[r + 1] - o_r);
        for (int j = (tid & 3); j < c_r; j += 4) {
            int g = r * 128 + j;
            int dst = (int)o_r + j;
            s_sel[dst] = kidxG[g];
            s_cb[dst] = b0a[g];
        }
        __syncthreads();
        rank_scatter(sc, false);
        __syncthreads();
        nms_groups(sc);
    }
    __syncthreads();

    int U1 = fast ? 255 : (sc == 0 ? 255 : 256);
    int U2 = 0;

    // ---- FALLBACK (adversarial only): banded selection over all keys ----
    if (s_kc < MAXDET) {
        {
            const uint4* kp = reinterpret_cast<const uint4*>(keysG);
            uint4* sk = reinterpret_cast<uint4*>(s_key);
#pragma unroll
            for (int j = 0; j < NBOX / 4 / BT2; ++j) sk[tid + j * BT2] = kp[tid + j * BT2];
        }
        s_hist[tid] = 0u;
        if (tid == 0) s_cnt = 0;
        __syncthreads();
        for (int j = 0; j < NBOX / BT2; ++j) {
            unsigned k = s_key[tid + j * BT2];
            if (k) {
                int b1, b2; bins_of(k, b1, b2);
                if (b1 < U1 || (b1 == U1 && b2 < U2)) atomicAdd(&s_hist[b1], 1u);
            }
        }
        while (true) {
            __syncthreads();
            if (wid == 0) {
                unsigned c0 = s_hist[lane * 4 + 0], c1s = s_hist[lane * 4 + 1];
                unsigned c2 = s_hist[lane * 4 + 2], c3 = s_hist[lane * 4 + 3];
                unsigned t3 = c3, t2 = c2 + t3, t1 = c1s + t2, t0 = c0 + t1;
                unsigned acc = t0;
#pragma unroll
                for (int d = 1; d < 64; d <<= 1) {
                    unsigned o = __shfl_down(acc, d);
                    if (lane + d < 64) acc += o;
                }
                unsigned excl = acc - t0;
                unsigned totalRem = __shfl(acc, 0);
                if (lane == 0) s_state = (totalRem == 0u) ? 2 : 0;
                if (totalRem != 0u) {
                    unsigned Kt = totalRem < (unsigned)KTGT ? totalRem : (unsigned)KTGT;
                    unsigned incq[4] = { excl + t0, excl + t1, excl + t2, excl + t3 };
                    unsigned abvq[4] = { excl + t1, excl + t2, excl + t3, excl };
#pragma unroll
                    for (int q = 0; q < 4; ++q) {
                        if (incq[q] >= Kt && abvq[q] < Kt) {
                            s_B1 = lane * 4 + q; s_B2 = 0;
                            if (incq[q] > CAP) { s_state = 1; s_refKrem = (int)(Kt - abvq[q]); }
                        }
                    }
                }
            }
            __syncthreads();
            const int st = s_state;
            if (st == 2) break;
            const int B1 = s_B1;
            if (st == 1) {
                s_hist[tid] = 0u;
                __syncthreads();
                for (int j = 0; j < NBOX / BT2; ++j) {
                    unsigned k = s_key[tid + j * BT2];
                    if (k) {
                        int b1, b2; bins_of(k, b1, b2);
                        if ((b1 < U1 || (b1 == U1 && b2 < U2)) && b1 == B1)
                            atomicAdd(&s_hist[b2], 1u);
                    }
                }
                __syncthreads();
                if (wid == 0) {
                    unsigned c0 = s_hist[lane * 4 + 0], c1s = s_hist[lane * 4 + 1];
                    unsigned c2 = s_hist[lane * 4 + 2], c3 = s_hist[lane * 4 + 3];
                    unsigned t3 = c3, t2 = c2 + t3, t1 = c1s + t2, t0 = c0 + t1;
                    unsigned acc = t0;
#pragma unroll
                    for (int d = 1; d < 64; d <<= 1) {
                        unsigned o = __shfl_down(acc, d);
                        if (lane + d < 64) acc += o;
                    }
                    unsigned excl = acc - t0;
                    unsigned Krem = (unsigned)s_refKrem;
                    unsigned incq[4] = { excl + t0, excl + t1, excl + t2, excl + t3 };
                    unsigned abvq[4] = { excl + t1, excl + t2, excl + t3, excl };
#pragma unroll
                    for (int q = 0; q < 4; ++q)
                        if (incq[q] >= Krem && abvq[q] < Krem) s_B2 = lane * 4 + q;
                }
                __syncthreads();
            }
            const int B2 = s_B2;
            for (int j = 0; j < NBOX / BT2; ++j) {
                int i = tid + j * BT2;
                unsigned k = s_key[i];
                if (k) {
                    int b1, b2; bins_of(k, b1, b2);
                    bool inr = (b1 < U1) || (b1 == U1 && b2 < U2);
                    bool sel = inr && ((b1 > B1) || (b1 == B1 && b2 >= B2));
                    if (sel) {
                        int pos = atomicAdd(&s_cnt, 1);
                        if (pos < CAP)
                            s_sel[pos] = (((u64)k) << 27) | (((u64)(NBOX - 1 - i)) << 14) | 0x3FFFull;
                    }
                }
            }
            __syncthreads();
            const int sc2 = s_cnt < CAP ? s_cnt : CAP;
            rank_scatter(sc2, true);
            __syncthreads();
            nms_groups(sc2);
            if (s_kc >= MAXDET) break;
            U1 = B1; U2 = B2;
            s_hist[tid] = 0u;
            if (tid == 0) s_cnt = 0;
            __syncthreads();
            for (int j = 0; j < NBOX / BT2; ++j) {
                unsigned k = s_key[tid + j * BT2];
                if (k) {
                    int b1, b2; bins_of(k, b1, b2);
                    if (b1 < U1 || (b1 == U1 && b2 < U2)) atomicAdd(&s_hist[b1], 1u);
                }
            }
        }
    }
    __syncthreads();

    // ---- output: 100 slots ----
    if (tid < MAXDET) {
        const int kc = s_kc;
        float* ob = out;                 // (100,12)
        float* od = out + MAXDET * 12;   // (100,3)
        float* os = out + MAXDET * 15;   // (100,)
        float* ol = out + MAXDET * 16;   // (100,) labels
        float* oo = out + MAXDET * 17;   // (100,) orient
        float4* obr = reinterpret_cast<float4*>(ob + tid * 12);
        if (tid < kc) {
            u64 v = s_kv[tid];
            float sscore = __uint_as_float(((unsigned)(v >> 27)) & 0x7FFFFFFFu);
            unsigned low = (unsigned)(v & 16383ull);
            obr[0] = s_kb[tid];
            os[tid] = sscore;
            ol[tid] = 0.0f;
            if (low < 8192u) {
                obr[1] = kp0a[low];
                obr[2] = kp1a[low];
                float4 dd = dda[low];
                od[tid * 3 + 0] = dd.x; od[tid * 3 + 1] = dd.y; od[tid * 3 + 2] = dd.z;
                oo[tid] = dd.w;
            } else {
                int idx = NBOX - 1 - (int)((v >> 14) & 8191ull);
                const float4* br = reinterpret_cast<const float4*>(boxes + idx * 12);
                obr[1] = br[1]; obr[2] = br[2];
                od[tid * 3 + 0] = dims[idx * 3 + 0];
                od[tid * 3 + 1] = dims[idx * 3 + 1];
                od[tid * 3 + 2] = dims[idx * 3 + 2];
                const float4 c0 = *reinterpret_cast<const float4*>(cls + idx * 8);
                const float4 c1 = *reinterpret_cast<const float4*>(cls + idx * 8 + 4);
                float m0 = fmaxf(c0.x, c1.x), m1 = fmaxf(c0.y, c1.y);
                float m2 = fmaxf(c0.z, c1.z), m3 = fmaxf(c0.w, c1.w);
                int o = 0; float best = m0;
                if (m1 > best) { best = m1; o = 1; }
                if (m2 > best) { best = m2; o = 2; }
                if (m3 > best) { best = m3; o = 3; }
                oo[tid] = (float)o;
            }
        } else {
            const float4 neg1 = make_float4(-1.f, -1.f, -1.f, -1.f);
            obr[0] = neg1; obr[1] = neg1; obr[2] = neg1;
            od[tid * 3 + 0] = -1.0f; od[tid * 3 + 1] = -1.0f; od[tid * 3 + 2] = -1.0f;
            os[tid] = -1.0f; ol[tid] = -1.0f; oo[tid] = -1.0f;
        }
    }
}

extern "C" void kernel_launch(void* const* d_in, const int* in_sizes, int n_in,
                              void* d_out, int out_size, void* d_ws, size_t ws_size,
                              hipStream_t stream) {
    const float* boxes = (const float*)d_in[0];
    const float* dims  = (const float*)d_in[1];
    const float* cls   = (const float*)d_in[2];
    float* out = (float*)d_out;
    unsigned char* ws = (unsigned char*)d_ws;
    unsigned* keys = (unsigned*)(ws + WS_KEYS);
    unsigned* cnts = (unsigned*)(ws + WS_CNTS);
    u64* kidx      = (u64*)(ws + WS_KIDX);
    float4* b0a    = (float4*)(ws + WS_B0);
    float4* kp0a   = (float4*)(ws + WS_KP0);
    float4* kp1a   = (float4*)(ws + WS_KP1);
    float4* dda    = (float4*)(ws + WS_DD);
    (void)in_sizes; (void)n_in; (void)out_size; (void)ws_size;
    score_push_kernel<<<NBOX / 128, 128, 0, stream>>>(boxes, dims, cls, keys, cnts, kidx, b0a, kp0a, kp1a, dda);
    nms_out_kernel<<<1, BT2, 0, stream>>>(boxes, dims, cls, keys, cnts, kidx, b0a, kp0a, kp1a, dda, out);
}

// Round 9
// 27.737 us; speedup vs baseline: 1.0074x; 1.0074x over previous
//
#include <hip/hip_runtime.h>

#define NBOX 8192
#define BT 1024
#define MAXDET 100
#define SCORE_T 0.05f
#define NMS_T 0.5f
#define CAP 1024
#define CAPM 384
#define NWMAX 6
#define KTGT 128
#define TOPBIN_T 0.99609375f   // 255/256: top value-uniform bin

typedef unsigned long long u64;

__device__ __forceinline__ float rl_f(float v, int j) {
    return __int_as_float(__builtin_amdgcn_readlane(__float_as_int(v), j));
}

__device__ __forceinline__ float iou_fn(float x1, float y1, float x2, float y2, float area,
                                        float bx1, float by1, float bx2, float by2, float barea) {
    float iw = fminf(x2, bx2) - fmaxf(x1, bx1);
    float ih = fminf(y2, by2) - fmaxf(y1, by1);
    iw = fmaxf(iw, 0.0f);
    ih = fmaxf(ih, 0.0f);
    float inter = iw * ih;
    return inter / fmaxf(area + barea - inter, 1e-8f);
}

__device__ __forceinline__ void bins_of(unsigned k, int& b1, int& b2) {
    float s = __uint_as_float(k & 0x7FFFFFFFu);
    b1 = (int)(s * 256.0f); if (b1 > 255) b1 = 255;
    b2 = (int)(s * 65536.0f) & 255;
}

// ================= HOT KERNEL: sort-free exact greedy via mask fixpoint =================
__global__ __launch_bounds__(BT) void hot_kernel(
    const float* __restrict__ boxes, const float* __restrict__ dims,
    const float* __restrict__ cls, unsigned* __restrict__ flagG,
    float* __restrict__ out) {
    __shared__ u64 s_sel[CAPM];          // packed (key<<13 | inv_idx)
    __shared__ float4 s_cb[CAPM];        // candidate box x1y1x2y2
    __shared__ unsigned char s_or[CAPM]; // orient
    __shared__ u64 s_gt[NWMAX][CAPM];    // key_j > key_t masks (word-major)
    __shared__ u64 s_sg[NWMAX][CAPM];    // gt && iou>thr
    __shared__ u64 s_K[NWMAX], s_U[NWMAX];
    __shared__ int s_cnt;

    const int tid = threadIdx.x;
    const int lane = tid & 63;
    const int w = tid >> 6;

    if (tid == 0) s_cnt = 0;
    __syncthreads();

    // ---- P1: score + push top-bin candidates ----
#pragma unroll
    for (int j = 0; j < NBOX / BT; ++j) {
        int i = tid + j * BT;
        const float4 c0 = *reinterpret_cast<const float4*>(cls + i * 8);
        const float4 c1 = *reinterpret_cast<const float4*>(cls + i * 8 + 4);
        float m0 = fmaxf(c0.x, c1.x), m1 = fmaxf(c0.y, c1.y);
        float m2 = fmaxf(c0.z, c1.z), m3 = fmaxf(c0.w, c1.w);
        float s = fmaxf(fmaxf(m0, m1), fmaxf(m2, m3));
        if (s > SCORE_T && s >= TOPBIN_T) {
            unsigned u = __float_as_uint(s);
            unsigned key = (u >> 31) ? ~u : (u | 0x80000000u);
            int o = 0; float best = m0;
            if (m1 > best) { best = m1; o = 1; }
            if (m2 > best) { best = m2; o = 2; }
            if (m3 > best) { best = m3; o = 3; }
            int pos = atomicAdd(&s_cnt, 1);
            if (pos < CAPM) {
                s_sel[pos] = (((u64)key) << 13) | (unsigned)(NBOX - 1 - i);
                s_cb[pos] = *reinterpret_cast<const float4*>(boxes + i * 12);
                s_or[pos] = (unsigned char)o;
            }
        }
    }
    __syncthreads();
    const int cnt = s_cnt;
    if (cnt == 0 || cnt > CAPM) {
        if (tid == 0) flagG[0] = 1u;   // fallback kernel solves from scratch
        return;
    }
    const int NW = (cnt + 63) >> 6;

    // ---- all-pairs masks: thread p -> (q = p/cnt, t = p%cnt), one 64-bit word ----
    const int tot = NW * cnt;
    for (int p = tid; p < tot; p += BT) {
        int q = p / cnt;
        int t = p - q * cnt;
        u64 selt = s_sel[t];
        float4 bt = s_cb[t];
        float x1 = bt.x, y1 = bt.y, x2 = bt.z, y2 = bt.w;
        float area = (x2 - x1) * (y2 - y1);
        int jbase = q << 6;
        int jmax = cnt - jbase; if (jmax > 64) jmax = 64;
        u64 g = 0ull, sg = 0ull;
        for (int jj = 0; jj < jmax; ++jj) {
            int jdx = jbase + jj;
            u64 selj = s_sel[jdx];
            float4 bj = s_cb[jdx];
            float barea = (bj.z - bj.x) * (bj.w - bj.y);
            float iou = iou_fn(x1, y1, x2, y2, area, bj.x, bj.y, bj.z, bj.w, barea);
            if (selj > selt) {
                u64 bit = 1ull << jj;
                g |= bit;
                if (iou > NMS_T) sg |= bit;
            }
        }
        s_gt[q][t] = g;
        s_sg[q][t] = sg;
    }
    if (tid < NWMAX) {
        int base = tid << 6;
        u64 uw = (cnt <= base) ? 0ull
               : ((cnt - base >= 64) ? ~0ull : ((1ull << (cnt - base)) - 1ull));
        s_U[tid] = uw;
        s_K[tid] = 0ull;
    }
    __syncthreads();

    // ---- fixpoint: exact greedy (>=1 decision per iteration guaranteed) ----
    const int t = tid;
    const bool have = t < cnt;
    for (int it = 0; it < CAPM; ++it) {
        bool undec = have && ((s_U[t >> 6] >> (t & 63)) & 1ull);
        u64 deadm = 0ull, blkm = 0ull;
        if (undec) {
            for (int q = 0; q < NW; ++q) {
                u64 sg = s_sg[q][t];
                deadm |= sg & s_K[q];
                blkm  |= sg & s_U[q];
            }
        }
        bool toDead = undec && (deadm != 0ull);
        bool toKept = undec && (deadm == 0ull) && (blkm == 0ull);
        u64 dW = __ballot(toDead);
        u64 kW = __ballot(toKept);
        if (lane == 0 && w < NW) {
            s_K[w] |= kW;
            s_U[w] &= ~(kW | dW);
        }
        __syncthreads();
        u64 anyU = 0ull;
        for (int q = 0; q < NW; ++q) anyU |= s_U[q];
        if (anyU == 0ull) break;
        __syncthreads();
    }

    // ---- count kept ----
    int kcnt = 0;
    for (int q = 0; q < NW; ++q) kcnt += (int)__popcll(s_K[q]);
    if (kcnt < MAXDET) {
        if (tid == 0) flagG[0] = 1u;   // need lower score bands: fallback redoes everything
        return;
    }
    if (tid == 0) flagG[0] = 0u;

    // ---- output: kept & rank<100 write slot=rank; pad handled by tid<100 ----
    float* ob = out;                 // (100,12)
    float* od = out + MAXDET * 12;   // (100,3)
    float* os = out + MAXDET * 15;   // (100,)
    float* ol = out + MAXDET * 16;   // (100,) labels
    float* oo = out + MAXDET * 17;   // (100,) orient
    if (have && ((s_K[t >> 6] >> (t & 63)) & 1ull)) {
        int rank = 0;
        for (int q = 0; q < NW; ++q) rank += (int)__popcll(s_gt[q][t] & s_K[q]);
        if (rank < MAXDET) {
            u64 v = s_sel[t];
            int idx = NBOX - 1 - (int)(v & 8191ull);
            float sscore = __uint_as_float(((unsigned)(v >> 13)) & 0x7FFFFFFFu);
            float4* obr = reinterpret_cast<float4*>(ob + rank * 12);
            const float4* br = reinterpret_cast<const float4*>(boxes + idx * 12);
            obr[0] = s_cb[t];
            obr[1] = br[1];
            obr[2] = br[2];
            od[rank * 3 + 0] = dims[idx * 3 + 0];
            od[rank * 3 + 1] = dims[idx * 3 + 1];
            od[rank * 3 + 2] = dims[idx * 3 + 2];
            os[rank] = sscore;
            ol[rank] = 0.0f;
            oo[rank] = (float)s_or[t];
        }
    }
    // kcnt >= 100 here, so no -1 padding needed (all 100 slots written above)
}

// ================= FALLBACK KERNEL (adversarial inputs only): proven R7 solver =================
__global__ __launch_bounds__(BT) void fallback_kernel(
    const float* __restrict__ boxes, const float* __restrict__ dims,
    const float* __restrict__ cls, const unsigned* __restrict__ flagG,
    float* __restrict__ out) {
    if (flagG[0] == 0u) return;
    __shared__ unsigned s_key[NBOX];
    __shared__ unsigned s_hist[256];
    __shared__ u64 s_sel[CAP];
    __shared__ u64 s_srt[CAP];
    __shared__ unsigned short s_srtpos[CAP];
    __shared__ float4 s_cb[CAP];
    __shared__ float4 s_bb[128];
    __shared__ float s_bar[128];
    __shared__ float4 s_kb[MAXDET];
    __shared__ float s_karea[MAXDET], s_kscore[MAXDET];
    __shared__ int s_ksel[MAXDET];
    __shared__ int s_kc, s_cnt, s_B1, s_B2, s_state, s_refKrem;
    __shared__ u64 s_alive0;

    const int tid = threadIdx.x;
    const int lane = tid & 63;
    const int wid = tid >> 6;

    auto rank_scatter = [&](int sc, bool loadBox) {
        if (tid < sc) {
            u64 mine = s_sel[tid];
            float4 pb = make_float4(0.f, 0.f, 0.f, 0.f);
            if (loadBox) {
                int bidx = NBOX - 1 - (int)(mine & 8191ull);
                pb = *reinterpret_cast<const float4*>(boxes + bidx * 12);
            }
            int rank = 0;
            int j = 0;
            for (; j + 8 <= sc; j += 8) {
                u64 a0 = s_sel[j + 0], a1 = s_sel[j + 1], a2 = s_sel[j + 2], a3 = s_sel[j + 3];
                u64 a4 = s_sel[j + 4], a5 = s_sel[j + 5], a6 = s_sel[j + 6], a7 = s_sel[j + 7];
                rank += (int)(a0 > mine) + (int)(a1 > mine) + (int)(a2 > mine) + (int)(a3 > mine)
                      + (int)(a4 > mine) + (int)(a5 > mine) + (int)(a6 > mine) + (int)(a7 > mine);
            }
            for (; j < sc; ++j) rank += (s_sel[j] > mine) ? 1 : 0;
            s_srt[rank] = mine;
            s_srtpos[rank] = (unsigned short)tid;
            if (loadBox) s_cb[tid] = pb;
        }
    };

    auto nms_groups = [&](int scN) {
        for (int base = 0; base < scN && s_kc < MAXDET; base += 128) {
            const int kc0 = s_kc;
            float x1 = 0.f, y1 = 0.f, x2 = 0.f, y2 = 0.f, area = 0.f, sscore = 0.f;
            int sidx = 0; bool have = false;
            if (wid < 2) {
                int p = base + wid * 64 + lane;
                have = p < scN;
                u64 v = have ? s_srt[p] : 0ull;
                int cp = have ? (int)s_srtpos[p] : 0;
                sidx = NBOX - 1 - (int)(v & 8191ull);
                sscore = __uint_as_float(((unsigned)(v >> 13)) & 0x7FFFFFFFu);
                float4 b = s_cb[cp];
                if (have) { x1 = b.x; y1 = b.y; x2 = b.z; y2 = b.w; area = (x2 - x1) * (y2 - y1); }
                int sl = wid * 64 + lane;
                s_bb[sl] = make_float4(x1, y1, x2, y2); s_bar[sl] = area;
            }
            __syncthreads();
            if (wid == 0) {
                bool cand = have;
                for (int k = 0; k < kc0; ++k) {
                    float4 kb = s_kb[k];
                    float iou = iou_fn(x1, y1, x2, y2, area, kb.x, kb.y, kb.z, kb.w, s_karea[k]);
                    cand = cand && !(iou > NMS_T);
                }
                u64 m = 0ull;
#pragma unroll 8
                for (int j = 0; j < 64; ++j) {
                    float iou = iou_fn(x1, y1, x2, y2, area,
                                       rl_f(x1, j), rl_f(y1, j), rl_f(x2, j), rl_f(y2, j), rl_f(area, j));
                    if ((iou > NMS_T) && (j < lane)) m |= (1ull << j);
                }
                u64 alive = __ballot(cand);
                u64 conf = __ballot((m & alive) != 0ull) & alive;
                while (conf) {
                    int i = (int)__builtin_ctzll(conf);
                    bool deadI = (lane == i) && ((m & alive) != 0ull);
                    u64 d = __ballot(deadI);
                    alive &= ~d; conf &= ~(d | (1ull << i));
                }
                int rank = (int)__popcll(alive & ((1ull << lane) - 1ull));
                int slot = kc0 + rank;
                if (((alive >> lane) & 1ull) && slot < MAXDET) {
                    s_kb[slot] = make_float4(x1, y1, x2, y2);
                    s_karea[slot] = area; s_kscore[slot] = sscore; s_ksel[slot] = sidx;
                }
                if (lane == 0) s_alive0 = alive;
            }
            u64 m_low = 0ull, m_high = 0ull;
            bool cand1 = have;
            if (wid == 1) {
                for (int k = 0; k < kc0; ++k) {
                    float4 kb = s_kb[k];
                    float iou = iou_fn(x1, y1, x2, y2, area, kb.x, kb.y, kb.z, kb.w, s_karea[k]);
                    cand1 = cand1 && !(iou > NMS_T);
                }
#pragma unroll 8
                for (int j = 0; j < 64; ++j) {
                    float4 bb = s_bb[j];
                    float iou = iou_fn(x1, y1, x2, y2, area, bb.x, bb.y, bb.z, bb.w, s_bar[j]);
                    if (iou > NMS_T) m_low |= (1ull << j);
                }
#pragma unroll 8
                for (int j = 0; j < 64; ++j) {
                    float iou = iou_fn(x1, y1, x2, y2, area,
                                       rl_f(x1, j), rl_f(y1, j), rl_f(x2, j), rl_f(y2, j), rl_f(area, j));
                    if ((iou > NMS_T) && (j < lane)) m_high |= (1ull << j);
                }
            }
            __syncthreads();
            if (wid == 1) {
                u64 alive0 = s_alive0;
                int popc0 = (int)__popcll(alive0);
                bool cand = cand1 && ((m_low & alive0) == 0ull);
                u64 alive = __ballot(cand);
                u64 conf = __ballot((m_high & alive) != 0ull) & alive;
                while (conf) {
                    int i = (int)__builtin_ctzll(conf);
                    bool deadI = (lane == i) && ((m_high & alive) != 0ull);
                    u64 d = __ballot(deadI);
                    alive &= ~d; conf &= ~(d | (1ull << i));
                }
                int rank = (int)__popcll(alive & ((1ull << lane) - 1ull));
                int slot = kc0 + popc0 + rank;
                if (((alive >> lane) & 1ull) && slot < MAXDET) {
                    s_kb[slot] = make_float4(x1, y1, x2, y2);
                    s_karea[slot] = area; s_kscore[slot] = sscore; s_ksel[slot] = sidx;
                }
                if (lane == 0) {
                    int nk = kc0 + popc0 + (int)__popcll(alive);
                    s_kc = nk > MAXDET ? MAXDET : nk;
                }
            }
            __syncthreads();
        }
    };

    unsigned keyr[8];
#pragma unroll
    for (int j = 0; j < NBOX / BT; ++j) {
        int i = tid + j * BT;
        const float4 c0 = *reinterpret_cast<const float4*>(cls + i * 8);
        const float4 c1 = *reinterpret_cast<const float4*>(cls + i * 8 + 4);
        float s = fmaxf(fmaxf(fmaxf(c0.x, c1.x), fmaxf(c0.y, c1.y)),
                        fmaxf(fmaxf(c0.z, c1.z), fmaxf(c0.w, c1.w)));
        unsigned u = __float_as_uint(s);
        unsigned key = (u >> 31) ? ~u : (u | 0x80000000u);
        key = (s > SCORE_T) ? key : 0u;
        keyr[j] = key;
        s_key[i] = key;
    }
    if (tid == 0) { s_kc = 0; s_cnt = 0; }
    __syncthreads();
#pragma unroll
    for (int j = 0; j < NBOX / BT; ++j) {
        unsigned k = keyr[j];
        if (k) {
            float s = __uint_as_float(k & 0x7FFFFFFFu);
            if (s >= TOPBIN_T) {
                int pos = atomicAdd(&s_cnt, 1);
                if (pos < CAP) {
                    int i = tid + j * BT;
                    s_sel[pos] = (((u64)k) << 13) | (unsigned)(NBOX - 1 - i);
                    s_cb[pos] = *reinterpret_cast<const float4*>(boxes + i * 12);
                }
            }
        }
    }
    __syncthreads();
    const int cnt0 = s_cnt;
    const bool ovf = cnt0 > CAP;
    if (!ovf && cnt0 > 0) {
        rank_scatter(cnt0, false);
        __syncthreads();
        nms_groups(cnt0);
    }
    int U1 = ovf ? 256 : 255;
    int U2 = 0;
    if (s_kc < MAXDET) {
        if (tid < 256) s_hist[tid] = 0u;
        if (tid == 0) s_cnt = 0;
        __syncthreads();
        for (int j = 0; j < NBOX / BT; ++j) {
            unsigned k = s_key[tid + j * BT];
            if (k) {
                int b1, b2; bins_of(k, b1, b2);
                if (b1 < U1 || (b1 == U1 && b2 < U2)) atomicAdd(&s_hist[b1], 1u);
            }
        }
        while (true) {
            __syncthreads();
            if (wid == 0) {
                unsigned c0 = s_hist[lane * 4 + 0], c1s = s_hist[lane * 4 + 1];
                unsigned c2 = s_hist[lane * 4 + 2], c3 = s_hist[lane * 4 + 3];
                unsigned t3 = c3, t2 = c2 + t3, t1 = c1s + t2, t0 = c0 + t1;
                unsigned acc = t0;
#pragma unroll
                for (int d = 1; d < 64; d <<= 1) {
                    unsigned o = __shfl_down(acc, d);
                    if (lane + d < 64) acc += o;
                }
                unsigned excl = acc - t0;
                unsigned totalRem = __shfl(acc, 0);
                if (lane == 0) s_state = (totalRem == 0u) ? 2 : 0;
                if (totalRem != 0u) {
                    unsigned Kt = totalRem < (unsigned)KTGT ? totalRem : (unsigned)KTGT;
                    unsigned incq[4] = { excl + t0, excl + t1, excl + t2, excl + t3 };
                    unsigned abvq[4] = { excl + t1, excl + t2, excl + t3, excl };
#pragma unroll
                    for (int q = 0; q < 4; ++q) {
                        if (incq[q] >= Kt && abvq[q] < Kt) {
                            s_B1 = lane * 4 + q; s_B2 = 0;
                            if (incq[q] > CAP) { s_state = 1; s_refKrem = (int)(Kt - abvq[q]); }
                        }
                    }
                }
            }
            __syncthreads();
            const int st = s_state;
            if (st == 2) break;
            const int B1 = s_B1;
            if (st == 1) {
                if (tid < 256) s_hist[tid] = 0u;
                __syncthreads();
                for (int j = 0; j < NBOX / BT; ++j) {
                    unsigned k = s_key[tid + j * BT];
                    if (k) {
                        int b1, b2; bins_of(k, b1, b2);
                        if ((b1 < U1 || (b1 == U1 && b2 < U2)) && b1 == B1)
                            atomicAdd(&s_hist[b2], 1u);
                    }
                }
                __syncthreads();
                if (wid == 0) {
                    unsigned c0 = s_hist[lane * 4 + 0], c1s = s_hist[lane * 4 + 1];
                    unsigned c2 = s_hist[lane * 4 + 2], c3 = s_hist[lane * 4 + 3];
                    unsigned t3 = c3, t2 = c2 + t3, t1 = c1s + t2, t0 = c0 + t1;
                    unsigned acc = t0;
#pragma unroll
                    for (int d = 1; d < 64; d <<= 1) {
                        unsigned o = __shfl_down(acc, d);
                        if (lane + d < 64) acc += o;
                    }
                    unsigned excl = acc - t0;
                    unsigned Krem = (unsigned)s_refKrem;
                    unsigned incq[4] = { excl + t0, excl + t1, excl + t2, excl + t3 };
                    unsigned abvq[4] = { excl + t1, excl + t2, excl + t3, excl };
#pragma unroll
                    for (int q = 0; q < 4; ++q)
                        if (incq[q] >= Krem && abvq[q] < Krem) s_B2 = lane * 4 + q;
                }
                __syncthreads();
            }
            const int B2 = s_B2;
            for (int j = 0; j < NBOX / BT; ++j) {
                int i = tid + j * BT;
                unsigned k = s_key[i];
                if (k) {
                    int b1, b2; bins_of(k, b1, b2);
                    bool inr = (b1 < U1) || (b1 == U1 && b2 < U2);
                    bool sel = inr && ((b1 > B1) || (b1 == B1 && b2 >= B2));
                    if (sel) {
                        int pos = atomicAdd(&s_cnt, 1);
                        if (pos < CAP)
                            s_sel[pos] = (((u64)k) << 13) | (unsigned)(NBOX - 1 - i);
                    }
                }
            }
            __syncthreads();
            const int sc2 = s_cnt < CAP ? s_cnt : CAP;
            rank_scatter(sc2, true);
            __syncthreads();
            nms_groups(sc2);
            if (s_kc >= MAXDET) break;
            U1 = B1; U2 = B2;
            if (tid < 256) s_hist[tid] = 0u;
            if (tid == 0) s_cnt = 0;
            __syncthreads();
            for (int j = 0; j < NBOX / BT; ++j) {
                unsigned k = s_key[tid + j * BT];
                if (k) {
                    int b1, b2; bins_of(k, b1, b2);
                    if (b1 < U1 || (b1 == U1 && b2 < U2)) atomicAdd(&s_hist[b1], 1u);
                }
            }
        }
    }
    __syncthreads();
    if (tid < MAXDET) {
        const int kc = s_kc;
        float* ob = out;
        float* od = out + MAXDET * 12;
        float* os = out + MAXDET * 15;
        float* ol = out + MAXDET * 16;
        float* oo = out + MAXDET * 17;
        float4* obr = reinterpret_cast<float4*>(ob + tid * 12);
        if (tid < kc) {
            int sel = s_ksel[tid];
            const float4* br = reinterpret_cast<const float4*>(boxes + sel * 12);
            obr[0] = br[0]; obr[1] = br[1]; obr[2] = br[2];
            od[tid * 3 + 0] = dims[sel * 3 + 0];
            od[tid * 3 + 1] = dims[sel * 3 + 1];
            od[tid * 3 + 2] = dims[sel * 3 + 2];
            os[tid] = s_kscore[tid];
            ol[tid] = 0.0f;
            const float4 c0 = *reinterpret_cast<const float4*>(cls + sel * 8);
            const float4 c1 = *reinterpret_cast<const float4*>(cls + sel * 8 + 4);
            float m0 = fmaxf(c0.x, c1.x), m1 = fmaxf(c0.y, c1.y);
            float m2 = fmaxf(c0.z, c1.z), m3 = fmaxf(c0.w, c1.w);
            int o = 0; float best = m0;
            if (m1 > best) { best = m1; o = 1; }
            if (m2 > best) { best = m2; o = 2; }
            if (m3 > best) { best = m3; o = 3; }
            oo[tid] = (float)o;
        } else {
            const float4 neg1 = make_float4(-1.f, -1.f, -1.f, -1.f);
            obr[0] = neg1; obr[1] = neg1; obr[2] = neg1;
            od[tid * 3 + 0] = -1.0f; od[tid * 3 + 1] = -1.0f; od[tid * 3 + 2] = -1.0f;
            os[tid] = -1.0f; ol[tid] = -1.0f; oo[tid] = -1.0f;
        }
    }
}

extern "C" void kernel_launch(void* const* d_in, const int* in_sizes, int n_in,
                              void* d_out, int out_size, void* d_ws, size_t ws_size,
                              hipStream_t stream) {
    const float* boxes = (const float*)d_in[0];
    const float* dims  = (const float*)d_in[1];
    const float* cls   = (const float*)d_in[2];
    float* out = (float*)d_out;
    unsigned* flag = (unsigned*)d_ws;
    (void)in_sizes; (void)n_in; (void)out_size; (void)ws_size;
    hot_kernel<<<1, BT, 0, stream>>>(boxes, dims, cls, flag, out);
    fallback_kernel<<<1, BT, 0, stream>>>(boxes, dims, cls, flag, out);
}